// Round 11
// baseline (174.641 us; speedup 1.0000x reference)
//
#include <hip/hip_runtime.h>
#include <math.h>

// ---------------------------------------------------------------------------
// AmplitudeQuantumNet: conv1+bn+relu+pool -> conv2+bn+relu+pool -> fc+tanh ->
// 8-qubit statevector sim -> expvals -> 8->128->64->10 MLP head.
// R5: conv2 LDS XOR-swizzle. R7: fused conv1+conv2 (-9.3us).
// R8: barrier-free quantum. R11: shfl-dedup REGRESSED (reverted).
// R12: 4 blocks/CU resident (-1.4us) -> occupancy-quantization mostly wrong.
// R13: M-SPLIT conv12 across 2 blocks/image (2048 blocks). conv12=38us vs
//      ~18us pipe floor; gap is intra-block A->B->C serialization. Split
//      halves per-block critical path (7/6 mt, windowed 10-row tile, 25.7KB
//      LDS -> 6 blocks/CU) with ZERO added LDS traffic and only 2 dup rows
//      in phase A. Bit-identical arithmetic.
// R14/R15: identical resubmits of R13 (benches failed on infra, no data;
//      kernel re-audited: uniform barriers, in-bounds LDS, no hang paths).
// ---------------------------------------------------------------------------

#define B_SZ 1024

// workspace offsets (in floats)
#define OFF_FCWP   0            // ushort[1605632] fc_w B-fragments (bf16 hi/lo)
#define OFF_W2F    802816       // ushort[36864] conv2 B-fragments (bf16 hi/lo)
#define OFF_W1T    821248       // [9][32]     conv1 w transposed
#define OFF_SC1    821536       // [32]
#define OFF_SH1    821568       // [32]
#define OFF_SC2    821600      // [64]
#define OFF_SH2    821664      // [64]
#define OFF_H1     821728      // fc partials [14][1024][256] (ends 4491744)
#define OFF_P2WT   4500000     // [128][64] p2w transposed
#define OFF_H2P    7244256     // ushort h2hi[1024][3136] ++ h2lo[1024][3136]

#define KSPLIT_FC 14
#define KCHUNK_FC 224           // 3136 / 14, = 7 * 32

typedef __attribute__((ext_vector_type(8))) short s16x8;
typedef __attribute__((ext_vector_type(4))) float f32x4;

__constant__ float C_COS8[8] = {1.f, 0.70710678f, 0.f, -0.70710678f, -1.f, -0.70710678f, 0.f, 0.70710678f};
__constant__ float C_SIN8[8] = {0.f, 0.70710678f, 1.f, 0.70710678f, 0.f, -0.70710678f, -1.f, -0.70710678f};

__device__ __forceinline__ unsigned short bf16_rne(float f) {
  unsigned u = __float_as_uint(f);
  unsigned r = u + 0x7FFFu + ((u >> 16) & 1u);
  return (unsigned short)(r >> 16);
}
__device__ __forceinline__ int div14(int m) {        // exact for 0 <= m <= 207
  return __float2int_rz((float)m * 0.07142858f);
}
// XOR-swizzle for conv2 input tile (ushort index e = P*32 + q*8 + j):
// 16B slot q' = q ^ ((P>>1)&3). Bijective per 4-row group.
__device__ __forceinline__ int swz16(int e) {
  return e ^ (((e >> 6) & 3) << 3);
}

// ------------------------- prep: weight packing + bn folding ---------------
__global__ __launch_bounds__(256) void prep_kernel(
    const float* __restrict__ fc_w, const float* __restrict__ c2w, const float* __restrict__ c1w,
    const float* __restrict__ bn1g, const float* __restrict__ bn1b, const float* __restrict__ bn1m,
    const float* __restrict__ bn1v, const float* __restrict__ c1b,
    const float* __restrict__ bn2g, const float* __restrict__ bn2b, const float* __restrict__ bn2m,
    const float* __restrict__ bn2v, const float* __restrict__ c2b,
    const float* __restrict__ p2w,
    float* __restrict__ ws) {
  int g = blockIdx.x * 256 + threadIdx.x;   // < 802816

  // fc_w B-fragments (bf16 hi/lo): layout [kg 98][nt 16][part 2][lane 64][j 8]
  {
    int j = g & 7, lane = (g >> 3) & 63, nt = (g >> 9) & 15, kg = g >> 13;
    int n = nt * 16 + (lane & 15);
    int k = kg * 32 + ((lane >> 4) & 3) * 8 + j;
    float v = fc_w[n * 3136 + (k & 63) * 49 + (k >> 6)];
    unsigned short hi = bf16_rne(v);
    unsigned short lo = bf16_rne(v - __uint_as_float((unsigned)hi << 16));
    unsigned short* us = (unsigned short*)ws;   // OFF_FCWP == 0
    int base = ((kg * 16 + nt) * 2) * 512 + lane * 8 + j;
    us[base] = hi;
    us[base + 512] = lo;
  }

  if (g < 36864) {
    // conv2 B-fragments: g = ((w*9+t)*2+h)*512 + L*8 + j
    int j = g & 7, L = (g >> 3) & 63, rest = g >> 9;
    int h = rest & 1; rest >>= 1;
    int t = rest % 9, w = rest / 9;
    int occ = w * 16 + (L & 15);
    int ic  = (L >> 4) * 8 + j;
    float v = c2w[occ * 288 + ic * 9 + t];
    unsigned short hi = bf16_rne(v);
    unsigned short res = hi;
    if (h) res = bf16_rne(v - __uint_as_float((unsigned)hi << 16));
    ((unsigned short*)(ws + OFF_W2F))[g] = res;
  }
  if (g < 8192) {           // p2wT[k*64+j] = p2w[j*128+k]
    ws[OFF_P2WT + g] = p2w[(g & 63) * 128 + (g >> 6)];
  }
  if (g < 288) {            // w1T[k*32+oc] = c1w[oc*9+k]
    ws[OFF_W1T + g] = c1w[(g & 31) * 9 + (g >> 5)];
  }
  if (g < 32) {
    float inv = bn1g[g] / sqrtf(bn1v[g] + 1e-5f);
    ws[OFF_SC1 + g] = inv;
    ws[OFF_SH1 + g] = c1b[g] * inv + bn1b[g] - bn1m[g] * inv;
  }
  if (g < 64) {
    float inv = bn2g[g] / sqrtf(bn2v[g] + 1e-5f);
    ws[OFF_SC2 + g] = inv;
    ws[OFF_SH2 + g] = c2b[g] * inv + bn2b[g] - bn2m[g] * inv;
  }
}

// ------------------- FUSED conv1+conv2 (MFMA implicit GEMM) ----------------
// 2048 blocks: blockIdx.x = b*2 + hh. hh=0: output rows y 0-7 (mt 0-6, pooled
// ps 0-27); hh=1: y 8-13 (mt 7-12, ps 28-48).
// LDS (25728 B -> 6 blocks/CU via VGPR/LDS limits):
//  tile_hi [10][16][32] @0 (10240), tile_lo @10240 (10240),
//  xs [30][32] @20480 (3840), w1s @24320 (1152), sc1s/sh1s @25472 (256)
//  phase C overlay: conv_out per-wave [64][16] f32 (4 x 4096 = 16384)
// Window: tile row tw = padded_row - 8*hh (hh=0: rows 0-9; hh=1: rows 8-15).
__global__ __launch_bounds__(256, 4) void conv12_kernel(
    const float* __restrict__ x, const float* __restrict__ w1T,
    const float* __restrict__ sc1, const float* __restrict__ sh1,
    const float* __restrict__ w2f_f,
    const float* __restrict__ sc2, const float* __restrict__ sh2,
    unsigned short* __restrict__ h2hi, unsigned short* __restrict__ h2lo) {
  const int b = blockIdx.x >> 1, hh = blockIdx.x & 1;
  const int tid = threadIdx.x;
  const int lane = tid & 63, w = tid >> 6;

  __shared__ unsigned char lds_raw[25728];
  unsigned short* tile_hi = (unsigned short*)lds_raw;
  unsigned short* tile_lo = (unsigned short*)(lds_raw + 10240);
  float* xs  = (float*)(lds_raw + 20480);      // [30][32]
  float* w1s = (float*)(lds_raw + 24320);      // [288]
  float* sc1s = (float*)(lds_raw + 25472);     // [32]
  float* sh1s = (float*)(lds_raw + 25600);     // [32]
  float* conv_out = (float*)lds_raw;

  // ---- zero tiles + xs: bytes 0..24320 = 1520 float4 ----
  {
    float4* z = (float4*)lds_raw;
    for (int i = tid; i < 1520; i += 256) z[i] = make_float4(0.f, 0.f, 0.f, 0.f);
  }
  __syncthreads();

  const float* xb = x + b * 784;
  for (int i = tid; i < 784; i += 256) {
    int y = i / 28, c = i - y * 28;
    xs[(y + 1) * 32 + (c + 1)] = xb[i];
  }
  for (int i = tid; i < 288; i += 256) w1s[i] = w1T[i];
  if (tid < 32) { sc1s[tid] = sc1[tid]; sh1s[tid] = sh1[tid]; }
  __syncthreads();

  // ---- phase A: conv1+bn+relu+pool for this half's rows only ----
  // hh=0: py1 0-8 (9 rows); hh=1: py1 7-13 (7 rows). Identical math per item.
  const int nitems = (9 - 2 * hh) * 32;
  for (int t = tid; t < nitems; t += 256) {
    const int oc = t & 31, py = (t >> 5) + 7 * hh;
    float wv[9];
#pragma unroll
    for (int k = 0; k < 9; ++k) wv[k] = w1s[k * 32 + oc];
    float acc0[28], acc1[28];
#pragma unroll
    for (int j = 0; j < 28; ++j) { acc0[j] = 0.f; acc1[j] = 0.f; }
#pragma unroll
    for (int r = 0; r < 4; ++r) {
      const int pr = 2 * py + r;
      float row[32];
#pragma unroll
      for (int q = 0; q < 8; ++q) {
        float4 v = *(const float4*)&xs[pr * 32 + 4 * q];
        row[4 * q] = v.x; row[4 * q + 1] = v.y; row[4 * q + 2] = v.z; row[4 * q + 3] = v.w;
      }
      if (r <= 2) {
#pragma unroll
        for (int kx = 0; kx < 3; ++kx) {
          const float w1v = wv[r * 3 + kx];
#pragma unroll
          for (int xx = 0; xx < 28; ++xx) acc0[xx] = fmaf(row[xx + kx], w1v, acc0[xx]);
        }
      }
      if (r >= 1) {
#pragma unroll
        for (int kx = 0; kx < 3; ++kx) {
          const float w1v = wv[(r - 1) * 3 + kx];
#pragma unroll
          for (int xx = 0; xx < 28; ++xx) acc1[xx] = fmaf(row[xx + kx], w1v, acc1[xx]);
        }
      }
    }
    const float sc = sc1s[oc], sh = sh1s[oc];
    const int tw = py + 1 - 8 * hh;            // windowed tile row
#pragma unroll
    for (int px = 0; px < 14; ++px) {
      float v0 = fmaxf(fmaf(acc0[2 * px], sc, sh), 0.f);
      float v1 = fmaxf(fmaf(acc0[2 * px + 1], sc, sh), 0.f);
      float v2 = fmaxf(fmaf(acc1[2 * px], sc, sh), 0.f);
      float v3 = fmaxf(fmaf(acc1[2 * px + 1], sc, sh), 0.f);
      float vm = fmaxf(fmaxf(v0, v1), fmaxf(v2, v3));
      unsigned short hv = bf16_rne(vm);
      unsigned short lv = bf16_rne(vm - __uint_as_float((unsigned)hv << 16));
      const int e = swz16((tw * 16 + (px + 1)) * 32 + oc);
      tile_hi[e] = hv;
      tile_lo[e] = lv;
    }
  }
  __syncthreads();

  // ---- phase B: conv2 B-fragments + MFMA loop over this half's mt ----
  const unsigned short* w2f = (const unsigned short*)w2f_f;
  s16x8 bf[9][2];
#pragma unroll
  for (int t = 0; t < 9; ++t)
#pragma unroll
    for (int h = 0; h < 2; ++h)
      bf[t][h] = *(const s16x8*)&w2f[(((w * 9 + t) * 2 + h) << 9) + lane * 8];

  f32x4 acc[7];
#pragma unroll
  for (int i = 0; i < 7; ++i) acc[i] = (f32x4){0.f, 0.f, 0.f, 0.f};

  const int MT0 = 7 * hh;                      // hh=0: mt 0-6; hh=1: mt 7-12
  const int NMT = 7 - hh;
  const int kg8 = (lane >> 4) * 8;
  for (int i = 0; i < NMT; ++i) {
    const int mt = MT0 + i;
    const int m = mt * 16 + (lane & 15);
    const int y = div14(m), xx = m - y * 14;
    const int base = ((y - 8 * hh) * 16 + xx) * 32 + kg8;   // windowed row
#pragma unroll
    for (int dy = 0; dy < 3; ++dy) {
#pragma unroll
      for (int dx = 0; dx < 3; ++dx) {
        const int off = swz16(base + (dy * 16 + dx) * 32);
        s16x8 ah = *(s16x8*)&tile_hi[off];
        s16x8 al = *(s16x8*)&tile_lo[off];
        const int t = dy * 3 + dx;
        acc[i] = __builtin_amdgcn_mfma_f32_16x16x32_bf16(ah, bf[t][0], acc[i], 0, 0, 0);
        acc[i] = __builtin_amdgcn_mfma_f32_16x16x32_bf16(ah, bf[t][1], acc[i], 0, 0, 0);
        acc[i] = __builtin_amdgcn_mfma_f32_16x16x32_bf16(al, bf[t][0], acc[i], 0, 0, 0);
      }
    }
  }
  __syncthreads();   // all tile reads done before conv_out overwrites LDS

  // ---- phase C: two chunks of {bn+relu write -> pool -> store} ----
  // chunk windows (wm, mt range, pooled-ps base/count):
  //  hh=0: (0, mt 0-3, ps 0..13), (48, mt 3-6, ps 14..27)
  //  hh=1: (112, mt 7-10, ps 28..41), (160, mt 10-12, ps 42..48)
  const int oc = w * 16 + (lane & 15);
  const float sc = sc2[oc], sh = sh2[oc];
  float* cw = conv_out + w * 1024;             // [64][16] f32 per wave
  const int quad = lane >> 4, oc16 = lane & 15;

#pragma unroll
  for (int ch = 0; ch < 2; ++ch) {
    const int wm = hh ? (ch ? 160 : 112) : (ch ? 48 : 0);
    const int mtLo = hh ? (ch ? 10 : 7) : (ch ? 3 : 0);
    const int mtHi = hh ? (ch ? 12 : 10) : (ch ? 6 : 3);
    const int pb = hh ? (ch ? 42 : 28) : (ch ? 14 : 0);
    const int pcnt = (hh && ch) ? 7 : 14;

    for (int mt = mtLo; mt <= mtHi; ++mt) {
      const int i = mt - MT0;
#pragma unroll
      for (int r = 0; r < 4; ++r) {
        const int m = mt * 16 + quad * 4 + r;
        if (m >= wm && m < wm + 64 && m < 196)
          cw[(m - wm) * 16 + oc16] = fmaxf(fmaf(acc[i][r], sc, sh), 0.f);
      }
    }
    __syncthreads();

    for (int j = 0; j < 4; ++j) {
      const int po = j * 4 + quad;
      if (po < pcnt) {
        const int ps = pb + po;
        const int py = (ps * 37) >> 8, px = ps - py * 7;
        const int m00 = py * 28 + px * 2;
        const int c0 = (m00 - wm) * 16 + oc16;
        float v0 = cw[c0], v1 = cw[c0 + 16], v2 = cw[c0 + 224], v3 = cw[c0 + 240];
        float vm = fmaxf(fmaxf(v0, v1), fmaxf(v2, v3));
        unsigned short hv = bf16_rne(vm);
        const int idx = b * 3136 + ps * 64 + oc;
        h2hi[idx] = hv;
        h2lo[idx] = bf16_rne(vm - __uint_as_float((unsigned)hv << 16));
      }
    }
    __syncthreads();
  }
}

// ------------------------- fc: MFMA GEMM (split-bf16, split-K) --------------
__global__ __launch_bounds__(256) void fc_mfma_kernel(
    const unsigned short* __restrict__ h2hi, const unsigned short* __restrict__ h2lo,
    const unsigned short* __restrict__ Bfrag, float* __restrict__ Part) {
  __shared__ unsigned short Bs[4096];   // 8 KB: [nf 4][part 2][lane 64][j 8]
  const int tid = threadIdx.x;
  const int lane = tid & 63, w = tid >> 6;
  const int m0 = blockIdx.y * 64, nt0 = blockIdx.x * 4, z = blockIdx.z;
  const int kz = z * KCHUNK_FC;

  const int mrow = m0 + w * 16 + (lane & 15);
  const int kg8 = (lane >> 4) * 8;
  const unsigned short* arow_hi = h2hi + mrow * 3136;
  const unsigned short* arow_lo = h2lo + mrow * 3136;

  f32x4 acc[4];
#pragma unroll
  for (int i = 0; i < 4; ++i) acc[i] = (f32x4){0.f, 0.f, 0.f, 0.f};

  // prefetch chunk 0 A-fragments
  s16x8 ah = *(const s16x8*)(arow_hi + kz + kg8);
  s16x8 al = *(const s16x8*)(arow_lo + kz + kg8);

  for (int c = 0; c < 7; ++c) {
    const int kg = (kz >> 5) + c;
    {
      const uint4* src = (const uint4*)(Bfrag + (size_t)(kg * 16 + nt0) * 1024);
      uint4* dst = (uint4*)Bs;
      dst[tid] = src[tid];
      dst[tid + 256] = src[tid + 256];
    }
    s16x8 ah2, al2;
    if (c < 6) {
      const int k1 = kz + (c + 1) * 32;
      ah2 = *(const s16x8*)(arow_hi + k1 + kg8);
      al2 = *(const s16x8*)(arow_lo + k1 + kg8);
    }
    __syncthreads();

#pragma unroll
    for (int nf = 0; nf < 4; ++nf) {
      s16x8 bh = *(s16x8*)&Bs[(nf * 2 + 0) * 512 + lane * 8];
      s16x8 bl = *(s16x8*)&Bs[(nf * 2 + 1) * 512 + lane * 8];
      acc[nf] = __builtin_amdgcn_mfma_f32_16x16x32_bf16(ah, bh, acc[nf], 0, 0, 0);
      acc[nf] = __builtin_amdgcn_mfma_f32_16x16x32_bf16(ah, bl, acc[nf], 0, 0, 0);
      acc[nf] = __builtin_amdgcn_mfma_f32_16x16x32_bf16(al, bh, acc[nf], 0, 0, 0);
    }
    __syncthreads();
    if (c < 6) { ah = ah2; al = al2; }
  }

  float* dst = Part + (size_t)z * 262144;
  const int mbase = m0 + w * 16 + (lane >> 4) * 4;
  const int nbase = nt0 * 16 + (lane & 15);
#pragma unroll
  for (int nf = 0; nf < 4; ++nf) {
#pragma unroll
    for (int r = 0; r < 4; ++r) {
      dst[(mbase + r) * 256 + nbase + nf * 16] = acc[nf][r];
    }
  }
}

// ------------------------- quantum sim + MLP head (barrier-free) -----------
__global__ __launch_bounds__(256) void quantum_kernel(
    const float* __restrict__ Part, const float* __restrict__ fc_b,
    const float* __restrict__ qp,
    const float* __restrict__ p1w, const float* __restrict__ p1b,
    const float* __restrict__ p2wT, const float* __restrict__ p2b,
    const float* __restrict__ p3w, const float* __restrict__ p3b,
    float* __restrict__ out) {
  const int tid = threadIdx.x;
  const int lane = tid & 63, wv = tid >> 6;
  const int b = blockIdx.x * 4 + wv;
  __shared__ float csl[160];
  __shared__ float z1buf[4][128];
  __shared__ float z2buf[4][64];

  if (tid < 80) {
    float t = 0.5f * qp[tid];
    csl[2 * tid] = cosf(t);
    csl[2 * tid + 1] = sinf(t);
  }
  __syncthreads();   // the only barrier

  float f[4];
#pragma unroll
  for (int r = 0; r < 4; ++r) {
    const int n = r * 64 + lane;
    float a = fc_b[n];
#pragma unroll
    for (int z = 0; z < KSPLIT_FC; ++z) a += Part[z * 262144 + b * 256 + n];
    f[r] = tanhf(a);
  }
  float ss = (f[0] * f[0] + f[1] * f[1]) + (f[2] * f[2] + f[3] * f[3]);
#pragma unroll
  for (int off = 32; off >= 1; off >>= 1) ss += __shfl_xor(ss, off);
  const float inv = 1.0f / sqrtf(ss);
  float re[4], im[4];
#pragma unroll
  for (int r = 0; r < 4; ++r) { re[r] = f[r] * inv; im[r] = 0.f; }

  float dre[4], dim_[4];
#pragma unroll
  for (int r = 0; r < 4; ++r) {
    const int i = r * 64 + lane;
    const int k8 = (2 * __popc(i & 0xAA) + __popc(i & 0x55)) & 7;
    float dr = C_COS8[k8], di = C_SIN8[k8];
    int par = ((i >> 7) & (i >> 6)) ^ ((i >> 5) & (i >> 4)) ^ ((i >> 3) & (i >> 2)) ^ ((i >> 1) & i)
            ^ ((i >> 6) & (i >> 5)) ^ ((i >> 4) & (i >> 3)) ^ ((i >> 2) & (i >> 1));
    if (par & 1) { dr = -dr; di = -di; }
    dre[r] = dr; dim_[r] = di;
  }

  const float RS = 0.70710678118654752f;

  {  // H wire 0: partner slot r^2
    float nr[4], ni[4];
#pragma unroll
    for (int r = 0; r < 4; ++r) {
      const float sgn = (r & 2) ? -1.f : 1.f;
      nr[r] = fmaf(sgn, re[r], re[r ^ 2]) * RS;
      ni[r] = fmaf(sgn, im[r], im[r ^ 2]) * RS;
    }
#pragma unroll
    for (int r = 0; r < 4; ++r) { re[r] = nr[r]; im[r] = ni[r]; }
  }
  {  // H wire 1: partner slot r^1
    float nr[4], ni[4];
#pragma unroll
    for (int r = 0; r < 4; ++r) {
      const float sgn = (r & 1) ? -1.f : 1.f;
      nr[r] = fmaf(sgn, re[r], re[r ^ 1]) * RS;
      ni[r] = fmaf(sgn, im[r], im[r ^ 1]) * RS;
    }
#pragma unroll
    for (int r = 0; r < 4; ++r) { re[r] = nr[r]; im[r] = ni[r]; }
  }
#pragma unroll
  for (int w = 2; w < 8; ++w) {
    const int m = 1 << (7 - w);
    const float sgn = (lane & m) ? -1.f : 1.f;
#pragma unroll
    for (int r = 0; r < 4; ++r) {
      float pre = __shfl_xor(re[r], m);
      float pim = __shfl_xor(im[r], m);
      re[r] = fmaf(sgn, re[r], pre) * RS;
      im[r] = fmaf(sgn, im[r], pim) * RS;
    }
  }

  for (int layer = 0; layer < 10; ++layer) {
    const float* cs = &csl[16 * layer];
    {
      const float c = cs[0], s = cs[1];
      float nr[4], ni[4];
#pragma unroll
      for (int r = 0; r < 4; ++r) {
        nr[r] = fmaf(s, im[r ^ 2], c * re[r]);
        ni[r] = fmaf(-s, re[r ^ 2], c * im[r]);
      }
#pragma unroll
      for (int r = 0; r < 4; ++r) { re[r] = nr[r]; im[r] = ni[r]; }
    }
    {
      const float c = cs[2], s = cs[3];
      float nr[4], ni[4];
#pragma unroll
      for (int r = 0; r < 4; ++r) {
        nr[r] = fmaf(s, im[r ^ 1], c * re[r]);
        ni[r] = fmaf(-s, re[r ^ 1], c * im[r]);
      }
#pragma unroll
      for (int r = 0; r < 4; ++r) { re[r] = nr[r]; im[r] = ni[r]; }
    }
#pragma unroll
    for (int w = 2; w < 8; ++w) {
      const int m = 1 << (7 - w);
      const float c = cs[2 * w], s = cs[2 * w + 1];
#pragma unroll
      for (int r = 0; r < 4; ++r) {
        float pre = __shfl_xor(re[r], m);
        float pim = __shfl_xor(im[r], m);
        float nre = fmaf(s, pim, c * re[r]);
        float nim = fmaf(-s, pre, c * im[r]);
        if (w == 7) {
          float tre = nre * dre[r] - nim * dim_[r];
          nim = fmaf(nre, dim_[r], nim * dre[r]);
          nre = tre;
        }
        re[r] = nre; im[r] = nim;
      }
    }
  }

  float prb[4];
#pragma unroll
  for (int r = 0; r < 4; ++r) prb[r] = re[r] * re[r] + im[r] * im[r];
  float qv[8];
#pragma unroll
  for (int w = 0; w < 8; ++w) {
    float v;
    if (w == 0)      v = (prb[0] + prb[1]) - (prb[2] + prb[3]);
    else if (w == 1) v = (prb[0] + prb[2]) - (prb[1] + prb[3]);
    else {
      const int m = 1 << (7 - w);
      float s4 = (prb[0] + prb[1]) + (prb[2] + prb[3]);
      v = (lane & m) ? -s4 : s4;
    }
#pragma unroll
    for (int off = 32; off >= 1; off >>= 1) v += __shfl_xor(v, off);
    qv[w] = v;
  }

  {
    float a = p1b[lane], a2 = p1b[lane + 64];
#pragma unroll
    for (int k = 0; k < 8; ++k) {
      a  = fmaf(qv[k], p1w[lane * 8 + k], a);
      a2 = fmaf(qv[k], p1w[(lane + 64) * 8 + k], a2);
    }
    z1buf[wv][lane]      = fmaxf(a, 0.f);
    z1buf[wv][lane + 64] = fmaxf(a2, 0.f);
  }
  float acc2 = p2b[lane];
#pragma unroll 16
  for (int k = 0; k < 128; ++k)
    acc2 = fmaf(z1buf[wv][k], p2wT[k * 64 + lane], acc2);
  z2buf[wv][lane] = fmaxf(acc2, 0.f);

  if (lane < 10) {
    float a3 = p3b[lane];
#pragma unroll 16
    for (int k = 0; k < 64; ++k) a3 = fmaf(z2buf[wv][k], p3w[lane * 64 + k], a3);
    out[b * 10 + lane] = a3;
  }
}

// ---------------------------------------------------------------------------
extern "C" void kernel_launch(void* const* d_in, const int* in_sizes, int n_in,
                              void* d_out, int out_size, void* d_ws, size_t ws_size,
                              hipStream_t stream) {
  (void)in_sizes; (void)n_in; (void)out_size; (void)ws_size;
  const float* x    = (const float*)d_in[0];
  const float* c1w  = (const float*)d_in[1];
  const float* c1b  = (const float*)d_in[2];
  const float* bn1g = (const float*)d_in[3];
  const float* bn1b = (const float*)d_in[4];
  const float* bn1m = (const float*)d_in[5];
  const float* bn1v = (const float*)d_in[6];
  const float* c2w  = (const float*)d_in[7];
  const float* c2b  = (const float*)d_in[8];
  const float* bn2g = (const float*)d_in[9];
  const float* bn2b = (const float*)d_in[10];
  const float* bn2m = (const float*)d_in[11];
  const float* bn2v = (const float*)d_in[12];
  const float* fc_w = (const float*)d_in[13];
  const float* fc_b = (const float*)d_in[14];
  const float* qp   = (const float*)d_in[15];
  const float* p1w  = (const float*)d_in[16];
  const float* p1b  = (const float*)d_in[17];
  const float* p2w  = (const float*)d_in[18];
  const float* p2b  = (const float*)d_in[19];
  const float* p3w  = (const float*)d_in[20];
  const float* p3b  = (const float*)d_in[21];
  float* ws = (float*)d_ws;
  float* outp = (float*)d_out;

  unsigned short* h2hi = (unsigned short*)(ws + OFF_H2P);
  unsigned short* h2lo = h2hi + 3211264;
  const unsigned short* bfrag = (const unsigned short*)ws;   // OFF_FCWP == 0

  prep_kernel<<<3136, 256, 0, stream>>>(fc_w, c2w, c1w,
                                        bn1g, bn1b, bn1m, bn1v, c1b,
                                        bn2g, bn2b, bn2m, bn2v, c2b, p2w, ws);
  conv12_kernel<<<2 * B_SZ, 256, 0, stream>>>(x, ws + OFF_W1T, ws + OFF_SC1, ws + OFF_SH1,
                                              ws + OFF_W2F, ws + OFF_SC2, ws + OFF_SH2,
                                              h2hi, h2lo);
  fc_mfma_kernel<<<dim3(4, 16, KSPLIT_FC), 256, 0, stream>>>(h2hi, h2lo, bfrag, ws + OFF_H1);
  quantum_kernel<<<256, 256, 0, stream>>>(ws + OFF_H1, fc_b, qp, p1w, p1b,
                                          ws + OFF_P2WT, p2b, p3w, p3b, outp);
}

// Round 12
// 164.080 us; speedup vs baseline: 1.0644x; 1.0644x over previous
//
#include <hip/hip_runtime.h>
#include <math.h>

// ---------------------------------------------------------------------------
// AmplitudeQuantumNet: conv1+bn+relu+pool -> conv2+bn+relu+pool -> fc+tanh ->
// 8-qubit statevector sim (H layer, 10x [RX x8 + S/T phase + CZ diag]) ->
// expvals -> 8->128->64->10 MLP head.
// R3: conv2 as MFMA implicit GEMM (split-bf16, fp32-accurate).
// R4: fc as MFMA GEMM: h2 emitted as bf16 hi/lo, prep pre-packs fc_w frags.
// R5: conv2 LDS XOR-swizzle (bank-conflict fix, bit-identical). -2.7us.
// R7: fused conv1+conv2 (killed 51 MB h1 round-trip). -9.3us.
// R8: barrier-free quantum (4 amps/lane, wave-per-b). -0.9us.
// R9: conv12 3 blocks/CU; fc N=64 + A-dbuf. neutral.
// R11: shfl-dedup of phase-B LDS reads. REGRESSED +17us. Reverted.
// R12: 4 blocks/CU resident (LDS 38016, launch_bounds(256,4)). -1.4us. BEST.
// R13: m-split 2048 blocks. REGRESSED +9.7us (duplicated x/W2F staging:
//      FETCH 2.1->5.2MB, VALUBusy 31->50%). conv12's 936-b128 LDS floor
//      (~18.7us/CU) is a shared-pipe bound; splitting can't reduce it.
// R16: REVERT to R12 exactly (known-good 164.9us).
// ---------------------------------------------------------------------------

#define B_SZ 1024

// workspace offsets (in floats)
#define OFF_FCWP   0            // ushort[1605632] fc_w B-fragments (bf16 hi/lo)
#define OFF_W2F    802816       // ushort[36864] conv2 B-fragments (bf16 hi/lo)
#define OFF_W1T    821248       // [9][32]     conv1 w transposed
#define OFF_SC1    821536       // [32]
#define OFF_SH1    821568       // [32]
#define OFF_SC2    821600      // [64]
#define OFF_SH2    821664      // [64]
#define OFF_H1     821728      // fc partials [14][1024][256] (ends 4491744)
#define OFF_P2WT   4500000     // [128][64] p2w transposed
#define OFF_H2P    7244256     // ushort h2hi[1024][3136] ++ h2lo[1024][3136]

#define KSPLIT_FC 14
#define KCHUNK_FC 224           // 3136 / 14, = 7 * 32

typedef __attribute__((ext_vector_type(8))) short s16x8;
typedef __attribute__((ext_vector_type(4))) float f32x4;

__constant__ float C_COS8[8] = {1.f, 0.70710678f, 0.f, -0.70710678f, -1.f, -0.70710678f, 0.f, 0.70710678f};
__constant__ float C_SIN8[8] = {0.f, 0.70710678f, 1.f, 0.70710678f, 0.f, -0.70710678f, -1.f, -0.70710678f};

__device__ __forceinline__ unsigned short bf16_rne(float f) {
  unsigned u = __float_as_uint(f);
  unsigned r = u + 0x7FFFu + ((u >> 16) & 1u);
  return (unsigned short)(r >> 16);
}
__device__ __forceinline__ int div14(int m) {        // exact for 0 <= m <= 207
  return __float2int_rz((float)m * 0.07142858f);
}
// XOR-swizzle for conv2 input tile (ushort index e = P*32 + q*8 + j):
// 16B slot q' = q ^ ((P>>1)&3). Bijective per 4-row group.
__device__ __forceinline__ int swz16(int e) {
  return e ^ (((e >> 6) & 3) << 3);
}

// ------------------------- prep: weight packing + bn folding ---------------
__global__ __launch_bounds__(256) void prep_kernel(
    const float* __restrict__ fc_w, const float* __restrict__ c2w, const float* __restrict__ c1w,
    const float* __restrict__ bn1g, const float* __restrict__ bn1b, const float* __restrict__ bn1m,
    const float* __restrict__ bn1v, const float* __restrict__ c1b,
    const float* __restrict__ bn2g, const float* __restrict__ bn2b, const float* __restrict__ bn2m,
    const float* __restrict__ bn2v, const float* __restrict__ c2b,
    const float* __restrict__ p2w,
    float* __restrict__ ws) {
  int g = blockIdx.x * 256 + threadIdx.x;   // < 802816

  // fc_w B-fragments (bf16 hi/lo): layout [kg 98][nt 16][part 2][lane 64][j 8]
  {
    int j = g & 7, lane = (g >> 3) & 63, nt = (g >> 9) & 15, kg = g >> 13;
    int n = nt * 16 + (lane & 15);
    int k = kg * 32 + ((lane >> 4) & 3) * 8 + j;
    float v = fc_w[n * 3136 + (k & 63) * 49 + (k >> 6)];
    unsigned short hi = bf16_rne(v);
    unsigned short lo = bf16_rne(v - __uint_as_float((unsigned)hi << 16));
    unsigned short* us = (unsigned short*)ws;   // OFF_FCWP == 0
    int base = ((kg * 16 + nt) * 2) * 512 + lane * 8 + j;
    us[base] = hi;
    us[base + 512] = lo;
  }

  if (g < 36864) {
    // conv2 B-fragments: g = ((w*9+t)*2+h)*512 + L*8 + j
    int j = g & 7, L = (g >> 3) & 63, rest = g >> 9;
    int h = rest & 1; rest >>= 1;
    int t = rest % 9, w = rest / 9;
    int occ = w * 16 + (L & 15);
    int ic  = (L >> 4) * 8 + j;
    float v = c2w[occ * 288 + ic * 9 + t];
    unsigned short hi = bf16_rne(v);
    unsigned short res = hi;
    if (h) res = bf16_rne(v - __uint_as_float((unsigned)hi << 16));
    ((unsigned short*)(ws + OFF_W2F))[g] = res;
  }
  if (g < 8192) {           // p2wT[k*64+j] = p2w[j*128+k]
    ws[OFF_P2WT + g] = p2w[(g & 63) * 128 + (g >> 6)];
  }
  if (g < 288) {            // w1T[k*32+oc] = c1w[oc*9+k]
    ws[OFF_W1T + g] = c1w[(g & 31) * 9 + (g >> 5)];
  }
  if (g < 32) {
    float inv = bn1g[g] / sqrtf(bn1v[g] + 1e-5f);
    ws[OFF_SC1 + g] = inv;
    ws[OFF_SH1 + g] = c1b[g] * inv + bn1b[g] - bn1m[g] * inv;
  }
  if (g < 64) {
    float inv = bn2g[g] / sqrtf(bn2v[g] + 1e-5f);
    ws[OFF_SC2 + g] = inv;
    ws[OFF_SH2 + g] = c2b[g] * inv + bn2b[g] - bn2m[g] * inv;
  }
}

// ------------------- FUSED conv1+conv2 (MFMA implicit GEMM) ----------------
// in: x[b][28][28]; out: h2hi/h2lo[b][49][64] bf16 hi/lo.
// R12 LDS layout (38016 B total -> 4 blocks/CU):
//  phase A/B: tile_hi [16][16][32] @0 (16384), tile_lo @16384 (16384),
//             xs [30][32] f32 @32768 (3840), w1s @36608 (1152),
//             sc1s @37760 (128), sh1s @37888 (128)
//  phase C:   conv_out per-wave chunk, [112][16] fp32 max (4 x 7168 = 28672)
__global__ __launch_bounds__(256, 4) void conv12_kernel(
    const float* __restrict__ x, const float* __restrict__ w1T,
    const float* __restrict__ sc1, const float* __restrict__ sh1,
    const float* __restrict__ w2f_f,
    const float* __restrict__ sc2, const float* __restrict__ sh2,
    unsigned short* __restrict__ h2hi, unsigned short* __restrict__ h2lo) {
  const int b = blockIdx.x, tid = threadIdx.x;
  const int lane = tid & 63, w = tid >> 6;

  __shared__ unsigned char lds_raw[38016];
  unsigned short* tile_hi = (unsigned short*)lds_raw;
  unsigned short* tile_lo = (unsigned short*)(lds_raw + 16384);
  float* xs  = (float*)(lds_raw + 32768);      // [30][32]
  float* w1s = (float*)(lds_raw + 36608);      // [288]
  float* sc1s = (float*)(lds_raw + 37760);     // [32]
  float* sh1s = (float*)(lds_raw + 37888);     // [32]
  float* conv_out = (float*)lds_raw;

  // ---- zero tile (incl. padding) + xs region: bytes 0..36608 = 2288 f4 ----
  {
    float4* z = (float4*)lds_raw;
    for (int i = tid; i < 2288; i += 256) z[i] = make_float4(0.f, 0.f, 0.f, 0.f);
  }
  __syncthreads();

  const float* xb = x + b * 784;
  for (int i = tid; i < 784; i += 256) {
    int y = i / 28, c = i - y * 28;
    xs[(y + 1) * 32 + (c + 1)] = xb[i];
  }
  for (int i = tid; i < 288; i += 256) w1s[i] = w1T[i];
  if (tid < 32) { sc1s[tid] = sc1[tid]; sh1s[tid] = sh1[tid]; }
  __syncthreads();

  // ---- phase A: conv1+bn+relu+pool, stage bf16 hi/lo into swizzled tile ----
  for (int t = tid; t < 448; t += 256) {
    const int oc = t & 31, py = t >> 5;
    float wv[9];
#pragma unroll
    for (int k = 0; k < 9; ++k) wv[k] = w1s[k * 32 + oc];
    float acc0[28], acc1[28];
#pragma unroll
    for (int j = 0; j < 28; ++j) { acc0[j] = 0.f; acc1[j] = 0.f; }
#pragma unroll
    for (int r = 0; r < 4; ++r) {
      const int pr = 2 * py + r;
      float row[32];
#pragma unroll
      for (int q = 0; q < 8; ++q) {
        float4 v = *(const float4*)&xs[pr * 32 + 4 * q];
        row[4 * q] = v.x; row[4 * q + 1] = v.y; row[4 * q + 2] = v.z; row[4 * q + 3] = v.w;
      }
      if (r <= 2) {
#pragma unroll
        for (int kx = 0; kx < 3; ++kx) {
          const float w1v = wv[r * 3 + kx];
#pragma unroll
          for (int xx = 0; xx < 28; ++xx) acc0[xx] = fmaf(row[xx + kx], w1v, acc0[xx]);
        }
      }
      if (r >= 1) {
#pragma unroll
        for (int kx = 0; kx < 3; ++kx) {
          const float w1v = wv[(r - 1) * 3 + kx];
#pragma unroll
          for (int xx = 0; xx < 28; ++xx) acc1[xx] = fmaf(row[xx + kx], w1v, acc1[xx]);
        }
      }
    }
    const float sc = sc1s[oc], sh = sh1s[oc];
#pragma unroll
    for (int px = 0; px < 14; ++px) {
      float v0 = fmaxf(fmaf(acc0[2 * px], sc, sh), 0.f);
      float v1 = fmaxf(fmaf(acc0[2 * px + 1], sc, sh), 0.f);
      float v2 = fmaxf(fmaf(acc1[2 * px], sc, sh), 0.f);
      float v3 = fmaxf(fmaf(acc1[2 * px + 1], sc, sh), 0.f);
      float vm = fmaxf(fmaxf(v0, v1), fmaxf(v2, v3));
      unsigned short hv = bf16_rne(vm);
      unsigned short lv = bf16_rne(vm - __uint_as_float((unsigned)hv << 16));
      const int e = swz16(((py + 1) * 16 + (px + 1)) * 32 + oc);
      tile_hi[e] = hv;
      tile_lo[e] = lv;
    }
  }
  __syncthreads();

  // ---- phase B: conv2 B-fragments + MFMA main loop ----
  const unsigned short* w2f = (const unsigned short*)w2f_f;
  s16x8 bf[9][2];
#pragma unroll
  for (int t = 0; t < 9; ++t)
#pragma unroll
    for (int h = 0; h < 2; ++h)
      bf[t][h] = *(const s16x8*)&w2f[(((w * 9 + t) * 2 + h) << 9) + lane * 8];

  f32x4 acc[13];
#pragma unroll
  for (int i = 0; i < 13; ++i) acc[i] = (f32x4){0.f, 0.f, 0.f, 0.f};

  const int kg8 = (lane >> 4) * 8;
#pragma unroll
  for (int mt = 0; mt < 13; ++mt) {
    const int m = mt * 16 + (lane & 15);
    const int y = div14(m), xx = m - y * 14;
    const int base = (y * 16 + xx) * 32 + kg8;
#pragma unroll
    for (int dy = 0; dy < 3; ++dy) {
#pragma unroll
      for (int dx = 0; dx < 3; ++dx) {
        const int off = swz16(base + (dy * 16 + dx) * 32);
        s16x8 ah = *(s16x8*)&tile_hi[off];
        s16x8 al = *(s16x8*)&tile_lo[off];
        const int t = dy * 3 + dx;
        acc[mt] = __builtin_amdgcn_mfma_f32_16x16x32_bf16(ah, bf[t][0], acc[mt], 0, 0, 0);
        acc[mt] = __builtin_amdgcn_mfma_f32_16x16x32_bf16(ah, bf[t][1], acc[mt], 0, 0, 0);
        acc[mt] = __builtin_amdgcn_mfma_f32_16x16x32_bf16(al, bf[t][0], acc[mt], 0, 0, 0);
      }
    }
  }
  __syncthreads();   // all tile reads done before conv_out overwrites LDS

  // ---- phase C (chunked): bn+relu -> pool -> store, two halves ----
  const int oc = w * 16 + (lane & 15);
  const float sc = sc2[oc], sh = sh2[oc];

  // chunk 1: mt 0-6 (m 0-111), pool ps 0-27 (pooled rows 0-3)
  {
    float* cw = conv_out + w * 1792;   // 112*16 floats per wave
#pragma unroll
    for (int mt = 0; mt < 7; ++mt) {
#pragma unroll
      for (int r = 0; r < 4; ++r) {
        const int m = mt * 16 + (lane >> 4) * 4 + r;   // < 112
        cw[m * 16 + (lane & 15)] = fmaxf(fmaf(acc[mt][r], sc, sh), 0.f);
      }
    }
    __syncthreads();
#pragma unroll
    for (int i = 0; i < 7; ++i) {
      const int ps = i * 4 + (lane >> 4);              // 0..27 exact
      const int py = (ps * 37) >> 8, px = ps - py * 7;
      const int m00 = py * 28 + px * 2;
      const int c0 = m00 * 16 + (lane & 15);
      float v0 = cw[c0], v1 = cw[c0 + 16], v2 = cw[c0 + 224], v3 = cw[c0 + 240];
      float vm = fmaxf(fmaxf(v0, v1), fmaxf(v2, v3));
      unsigned short hv = bf16_rne(vm);
      const int idx = b * 3136 + ps * 64 + oc;
      h2hi[idx] = hv;
      h2lo[idx] = bf16_rne(vm - __uint_as_float((unsigned)hv << 16));
    }
  }
  __syncthreads();

  // chunk 2: mt 7-12 (m 112-195), pool ps 28-48 (pooled rows 4-6)
  {
    float* cw = conv_out + w * 1344;   // 84*16 floats per wave
#pragma unroll
    for (int mt = 7; mt < 13; ++mt) {
#pragma unroll
      for (int r = 0; r < 4; ++r) {
        const int m = mt * 16 + (lane >> 4) * 4 + r;
        if (m < 196) cw[(m - 112) * 16 + (lane & 15)] = fmaxf(fmaf(acc[mt][r], sc, sh), 0.f);
      }
    }
    __syncthreads();
#pragma unroll
    for (int i = 0; i < 6; ++i) {
      const int ps = 28 + i * 4 + (lane >> 4);
      if (ps < 49) {
        const int py = (ps * 37) >> 8, px = ps - py * 7;
        const int m00 = py * 28 + px * 2;
        const int c0 = (m00 - 112) * 16 + (lane & 15);
        float v0 = cw[c0], v1 = cw[c0 + 16], v2 = cw[c0 + 224], v3 = cw[c0 + 240];
        float vm = fmaxf(fmaxf(v0, v1), fmaxf(v2, v3));
        unsigned short hv = bf16_rne(vm);
        const int idx = b * 3136 + ps * 64 + oc;
        h2hi[idx] = hv;
        h2lo[idx] = bf16_rne(vm - __uint_as_float((unsigned)hv << 16));
      }
    }
  }
}

// ------------------------- fc: MFMA GEMM (split-bf16, split-K) --------------
__global__ __launch_bounds__(256) void fc_mfma_kernel(
    const unsigned short* __restrict__ h2hi, const unsigned short* __restrict__ h2lo,
    const unsigned short* __restrict__ Bfrag, float* __restrict__ Part) {
  __shared__ unsigned short Bs[4096];   // 8 KB: [nf 4][part 2][lane 64][j 8]
  const int tid = threadIdx.x;
  const int lane = tid & 63, w = tid >> 6;
  const int m0 = blockIdx.y * 64, nt0 = blockIdx.x * 4, z = blockIdx.z;
  const int kz = z * KCHUNK_FC;

  const int mrow = m0 + w * 16 + (lane & 15);
  const int kg8 = (lane >> 4) * 8;
  const unsigned short* arow_hi = h2hi + mrow * 3136;
  const unsigned short* arow_lo = h2lo + mrow * 3136;

  f32x4 acc[4];
#pragma unroll
  for (int i = 0; i < 4; ++i) acc[i] = (f32x4){0.f, 0.f, 0.f, 0.f};

  // prefetch chunk 0 A-fragments
  s16x8 ah = *(const s16x8*)(arow_hi + kz + kg8);
  s16x8 al = *(const s16x8*)(arow_lo + kz + kg8);

  for (int c = 0; c < 7; ++c) {
    const int kg = (kz >> 5) + c;
    // stage B chunk: 8 KB contiguous ([kg][nt0..nt0+3][2][512])
    {
      const uint4* src = (const uint4*)(Bfrag + (size_t)(kg * 16 + nt0) * 1024);
      uint4* dst = (uint4*)Bs;
      dst[tid] = src[tid];
      dst[tid + 256] = src[tid + 256];
    }
    // issue next chunk's A gathers before the barrier/MFMAs
    s16x8 ah2, al2;
    if (c < 6) {
      const int k1 = kz + (c + 1) * 32;
      ah2 = *(const s16x8*)(arow_hi + k1 + kg8);
      al2 = *(const s16x8*)(arow_lo + k1 + kg8);
    }
    __syncthreads();

#pragma unroll
    for (int nf = 0; nf < 4; ++nf) {
      s16x8 bh = *(s16x8*)&Bs[(nf * 2 + 0) * 512 + lane * 8];
      s16x8 bl = *(s16x8*)&Bs[(nf * 2 + 1) * 512 + lane * 8];
      acc[nf] = __builtin_amdgcn_mfma_f32_16x16x32_bf16(ah, bh, acc[nf], 0, 0, 0);
      acc[nf] = __builtin_amdgcn_mfma_f32_16x16x32_bf16(ah, bl, acc[nf], 0, 0, 0);
      acc[nf] = __builtin_amdgcn_mfma_f32_16x16x32_bf16(al, bh, acc[nf], 0, 0, 0);
    }
    __syncthreads();
    if (c < 6) { ah = ah2; al = al2; }
  }

  float* dst = Part + (size_t)z * 262144;
  const int mbase = m0 + w * 16 + (lane >> 4) * 4;
  const int nbase = nt0 * 16 + (lane & 15);
#pragma unroll
  for (int nf = 0; nf < 4; ++nf) {
#pragma unroll
    for (int r = 0; r < 4; ++r) {
      dst[(mbase + r) * 256 + nbase + nf * 16] = acc[nf][r];
    }
  }
}

// ------------------------- quantum sim + MLP head (barrier-free) -----------
// One wave per batch element; 4 amplitudes per lane: state i = r*64 + lane.
__global__ __launch_bounds__(256) void quantum_kernel(
    const float* __restrict__ Part, const float* __restrict__ fc_b,
    const float* __restrict__ qp,
    const float* __restrict__ p1w, const float* __restrict__ p1b,
    const float* __restrict__ p2wT, const float* __restrict__ p2b,
    const float* __restrict__ p3w, const float* __restrict__ p3b,
    float* __restrict__ out) {
  const int tid = threadIdx.x;
  const int lane = tid & 63, wv = tid >> 6;
  const int b = blockIdx.x * 4 + wv;
  __shared__ float csl[160];       // cos/sin of q_params/2
  __shared__ float z1buf[4][128];  // wave-private head scratch
  __shared__ float z2buf[4][64];

  if (tid < 80) {
    float t = 0.5f * qp[tid];
    csl[2 * tid] = cosf(t);
    csl[2 * tid + 1] = sinf(t);
  }
  __syncthreads();   // the only barrier

  // ---- feats: split-K reduce + bias + tanh; 4 n-indices per lane ----
  float f[4];
#pragma unroll
  for (int r = 0; r < 4; ++r) {
    const int n = r * 64 + lane;
    float a = fc_b[n];
#pragma unroll
    for (int z = 0; z < KSPLIT_FC; ++z) a += Part[z * 262144 + b * 256 + n];
    f[r] = tanhf(a);
  }
  float ss = (f[0] * f[0] + f[1] * f[1]) + (f[2] * f[2] + f[3] * f[3]);
#pragma unroll
  for (int off = 32; off >= 1; off >>= 1) ss += __shfl_xor(ss, off);
  const float inv = 1.0f / sqrtf(ss);
  float re[4], im[4];
#pragma unroll
  for (int r = 0; r < 4; ++r) { re[r] = f[r] * inv; im[r] = 0.f; }

  // ---- fixed diagonal per slot: S/T phases * CZ signs ----
  float dre[4], dim_[4];
#pragma unroll
  for (int r = 0; r < 4; ++r) {
    const int i = r * 64 + lane;
    const int k8 = (2 * __popc(i & 0xAA) + __popc(i & 0x55)) & 7;
    float dr = C_COS8[k8], di = C_SIN8[k8];
    int par = ((i >> 7) & (i >> 6)) ^ ((i >> 5) & (i >> 4)) ^ ((i >> 3) & (i >> 2)) ^ ((i >> 1) & i)
            ^ ((i >> 6) & (i >> 5)) ^ ((i >> 4) & (i >> 3)) ^ ((i >> 2) & (i >> 1));
    if (par & 1) { dr = -dr; di = -di; }
    dre[r] = dr; dim_[r] = di;
  }

  const float RS = 0.70710678118654752f;

  // ---- Hadamard layer ----
  {  // wire 0: partner slot r^2, sign from (r&2)
    float nr[4], ni[4];
#pragma unroll
    for (int r = 0; r < 4; ++r) {
      const float sgn = (r & 2) ? -1.f : 1.f;
      nr[r] = fmaf(sgn, re[r], re[r ^ 2]) * RS;
      ni[r] = fmaf(sgn, im[r], im[r ^ 2]) * RS;
    }
#pragma unroll
    for (int r = 0; r < 4; ++r) { re[r] = nr[r]; im[r] = ni[r]; }
  }
  {  // wire 1: partner slot r^1, sign from (r&1)
    float nr[4], ni[4];
#pragma unroll
    for (int r = 0; r < 4; ++r) {
      const float sgn = (r & 1) ? -1.f : 1.f;
      nr[r] = fmaf(sgn, re[r], re[r ^ 1]) * RS;
      ni[r] = fmaf(sgn, im[r], im[r ^ 1]) * RS;
    }
#pragma unroll
    for (int r = 0; r < 4; ++r) { re[r] = nr[r]; im[r] = ni[r]; }
  }
#pragma unroll
  for (int w = 2; w < 8; ++w) {
    const int m = 1 << (7 - w);
    const float sgn = (lane & m) ? -1.f : 1.f;
#pragma unroll
    for (int r = 0; r < 4; ++r) {
      float pre = __shfl_xor(re[r], m);
      float pim = __shfl_xor(im[r], m);
      re[r] = fmaf(sgn, re[r], pre) * RS;
      im[r] = fmaf(sgn, im[r], pim) * RS;
    }
  }

  // ---- 10 layers: 8 RX gates + diagonal (folded into wire-7 update) ----
  for (int layer = 0; layer < 10; ++layer) {
    const float* cs = &csl[16 * layer];
    {  // wire 0: partner r^2
      const float c = cs[0], s = cs[1];
      float nr[4], ni[4];
#pragma unroll
      for (int r = 0; r < 4; ++r) {
        nr[r] = fmaf(s, im[r ^ 2], c * re[r]);
        ni[r] = fmaf(-s, re[r ^ 2], c * im[r]);
      }
#pragma unroll
      for (int r = 0; r < 4; ++r) { re[r] = nr[r]; im[r] = ni[r]; }
    }
    {  // wire 1: partner r^1
      const float c = cs[2], s = cs[3];
      float nr[4], ni[4];
#pragma unroll
      for (int r = 0; r < 4; ++r) {
        nr[r] = fmaf(s, im[r ^ 1], c * re[r]);
        ni[r] = fmaf(-s, re[r ^ 1], c * im[r]);
      }
#pragma unroll
      for (int r = 0; r < 4; ++r) { re[r] = nr[r]; im[r] = ni[r]; }
    }
#pragma unroll
    for (int w = 2; w < 8; ++w) {
      const int m = 1 << (7 - w);
      const float c = cs[2 * w], s = cs[2 * w + 1];
#pragma unroll
      for (int r = 0; r < 4; ++r) {
        float pre = __shfl_xor(re[r], m);
        float pim = __shfl_xor(im[r], m);
        float nre = fmaf(s, pim, c * re[r]);
        float nim = fmaf(-s, pre, c * im[r]);
        if (w == 7) {
          float tre = nre * dre[r] - nim * dim_[r];
          nim = fmaf(nre, dim_[r], nim * dre[r]);
          nre = tre;
        }
        re[r] = nre; im[r] = nim;
      }
    }
  }

  // ---- expvals of PauliZ on each wire (all-lane butterfly) ----
  float prb[4];
#pragma unroll
  for (int r = 0; r < 4; ++r) prb[r] = re[r] * re[r] + im[r] * im[r];
  float qv[8];
#pragma unroll
  for (int w = 0; w < 8; ++w) {
    float v;
    if (w == 0)      v = (prb[0] + prb[1]) - (prb[2] + prb[3]);   // bit7 = r>>1
    else if (w == 1) v = (prb[0] + prb[2]) - (prb[1] + prb[3]);   // bit6 = r&1
    else {
      const int m = 1 << (7 - w);
      float s4 = (prb[0] + prb[1]) + (prb[2] + prb[3]);
      v = (lane & m) ? -s4 : s4;
    }
#pragma unroll
    for (int off = 32; off >= 1; off >>= 1) v += __shfl_xor(v, off);
    qv[w] = v;
  }

  // ---- head: 8 -> 128 -> 64 -> 10, per-wave ----
  {
    float a = p1b[lane], a2 = p1b[lane + 64];
#pragma unroll
    for (int k = 0; k < 8; ++k) {
      a  = fmaf(qv[k], p1w[lane * 8 + k], a);
      a2 = fmaf(qv[k], p1w[(lane + 64) * 8 + k], a2);
    }
    z1buf[wv][lane]      = fmaxf(a, 0.f);
    z1buf[wv][lane + 64] = fmaxf(a2, 0.f);
  }
  // within-wave LDS write->read; compiler inserts lgkmcnt
  float acc2 = p2b[lane];
#pragma unroll 16
  for (int k = 0; k < 128; ++k)
    acc2 = fmaf(z1buf[wv][k], p2wT[k * 64 + lane], acc2);
  z2buf[wv][lane] = fmaxf(acc2, 0.f);

  if (lane < 10) {
    float a3 = p3b[lane];
#pragma unroll 16
    for (int k = 0; k < 64; ++k) a3 = fmaf(z2buf[wv][k], p3w[lane * 64 + k], a3);
    out[b * 10 + lane] = a3;
  }
}

// ---------------------------------------------------------------------------
extern "C" void kernel_launch(void* const* d_in, const int* in_sizes, int n_in,
                              void* d_out, int out_size, void* d_ws, size_t ws_size,
                              hipStream_t stream) {
  (void)in_sizes; (void)n_in; (void)out_size; (void)ws_size;
  const float* x    = (const float*)d_in[0];
  const float* c1w  = (const float*)d_in[1];
  const float* c1b  = (const float*)d_in[2];
  const float* bn1g = (const float*)d_in[3];
  const float* bn1b = (const float*)d_in[4];
  const float* bn1m = (const float*)d_in[5];
  const float* bn1v = (const float*)d_in[6];
  const float* c2w  = (const float*)d_in[7];
  const float* c2b  = (const float*)d_in[8];
  const float* bn2g = (const float*)d_in[9];
  const float* bn2b = (const float*)d_in[10];
  const float* bn2m = (const float*)d_in[11];
  const float* bn2v = (const float*)d_in[12];
  const float* fc_w = (const float*)d_in[13];
  const float* fc_b = (const float*)d_in[14];
  const float* qp   = (const float*)d_in[15];
  const float* p1w  = (const float*)d_in[16];
  const float* p1b  = (const float*)d_in[17];
  const float* p2w  = (const float*)d_in[18];
  const float* p2b  = (const float*)d_in[19];
  const float* p3w  = (const float*)d_in[20];
  const float* p3b  = (const float*)d_in[21];
  float* ws = (float*)d_ws;
  float* outp = (float*)d_out;

  unsigned short* h2hi = (unsigned short*)(ws + OFF_H2P);
  unsigned short* h2lo = h2hi + 3211264;
  const unsigned short* bfrag = (const unsigned short*)ws;   // OFF_FCWP == 0

  prep_kernel<<<3136, 256, 0, stream>>>(fc_w, c2w, c1w,
                                        bn1g, bn1b, bn1m, bn1v, c1b,
                                        bn2g, bn2b, bn2m, bn2v, c2b, p2w, ws);
  conv12_kernel<<<B_SZ, 256, 0, stream>>>(x, ws + OFF_W1T, ws + OFF_SC1, ws + OFF_SH1,
                                          ws + OFF_W2F, ws + OFF_SC2, ws + OFF_SH2,
                                          h2hi, h2lo);
  fc_mfma_kernel<<<dim3(4, 16, KSPLIT_FC), 256, 0, stream>>>(h2hi, h2lo, bfrag, ws + OFF_H1);
  quantum_kernel<<<256, 256, 0, stream>>>(ws + OFF_H1, fc_b, qp, p1w, p1b,
                                          ws + OFF_P2WT, p2b, p3w, p3b, outp);
}